// Round 5
// baseline (127.172 us; speedup 1.0000x reference)
//
#include <hip/hip_runtime.h>
#include <hip/hip_bf16.h>
#include <math.h>

#define D_MODEL 2048
#define N_EXP   64
#define NTOK    16384           // 4 * 4096
#define NBLK    512             // NTOK / 32 tokens per block
#define NSTG    16              // K stages: 2048 / 128

typedef short bf16x8 __attribute__((ext_vector_type(8)));
typedef float f32x16 __attribute__((ext_vector_type(16)));
typedef unsigned int u32;

// out layout (floats)
#define OFF_PROBS 0
#define OFF_IDX   32768
#define OFF_MASK  65536
#define OFF_AUX   1114112
#define OFF_ENT   1114113

#define WF_PS 16384            // bf16x8 units per split-part (128 g * 2 n * 64)

#define MEMFENCE asm volatile("" ::: "memory")
// fence + barrier + fence: s_barrier alone is NOT a compiler memory fence;
// without the trailing fence the compiler may hoist next-stage LDS reads
// above the barrier (r9 failure: cross-wave stage rows read stale).
#define FULLBAR() do { MEMFENCE; __builtin_amdgcn_s_barrier(); MEMFENCE; \
                       __builtin_amdgcn_sched_barrier(0); } while (0)

__device__ __forceinline__ void split3(float xv, u32& h, u32& m, u32& l) {
  u32 xb = __builtin_bit_cast(u32, xv);
  u32 hb = xb & 0xFFFF0000u;
  float tf = xv - __builtin_bit_cast(float, hb);      // exact (Sterbenz)
  u32 tb = __builtin_bit_cast(u32, tf);
  u32 mb = tb & 0xFFFF0000u;
  float t2 = tf - __builtin_bit_cast(float, mb);      // exact; bf16-representable
  u32 lb = __builtin_bit_cast(u32, t2);
  h = hb >> 16; m = mb >> 16; l = lb >> 16;
}

__device__ __forceinline__ bool better(float a, int ia, float b, int ib) {
  return (a > b) || (a == b && ia < ib);
}

// W[64][2048] -> 3 bf16 parts in 32x32x16 B-fragment order. (verified r5-r8)
// r14: also zeroes the finalize tickets each launch (runs before fused).
__global__ __launch_bounds__(256) void wprep_kernel(
    const float* __restrict__ W, bf16x8* __restrict__ Wf,
    u32* __restrict__ tickets) {
  if (blockIdx.x == 0 && threadIdx.x < 65) tickets[threadIdx.x] = 0u;
  int gid  = blockIdx.x * 256 + threadIdx.x;   // 16384
  int g    = gid >> 7;
  int n    = (gid >> 6) & 1;
  int lane = gid & 63;
  int e    = n * 32 + (lane & 31);
  int k    = g * 16 + ((lane >> 5) << 3);
  const float* wr = W + (size_t)e * D_MODEL + k;
  bf16x8 hv, mv, lv;
#pragma unroll
  for (int j = 0; j < 8; ++j) {
    u32 h, m, l;
    split3(wr[j], h, m, l);
    hv[j] = (short)h; mv[j] = (short)m; lv[j] = (short)l;
  }
  Wf[gid]             = hv;
  Wf[WF_PS + gid]     = mv;
  Wf[2 * WF_PS + gid] = lv;
}

// Fused main loop: r12 (=r9) structure verbatim -- the verified 50.8us best.
// r13 post-mortem: wave-private staging regressed (53.4) -> loop is NOT
// barrier-lockstep-limited; keep the 4-buf row-major staging untouched.
// Contiguity-first staging: stage = 32 rows x 128 floats (512B/row). One
// glds instr = 1KB = two row-spans (lanes 0-31 row r, lanes 32-63 row r+1).
// 8 waves share the stage; wave w computes k-slice [st*128+w*16,+16).
// 4 bufs x 16KB; glds 2 stages ahead; counted vmcnt(8/6); 1 FULLBAR/stage.
// LDS swizzle: source chunk ^= row; read applies same XOR (involution).
// r14 NEW: in-kernel finalize via two-level ticket (replaces finalize_part +
// finalize_final dispatches). Summation trees replicated bit-exactly.
__global__ __launch_bounds__(512, 4) void fused_kernel(
    const float* __restrict__ x, const bf16x8* __restrict__ Wf,
    const float* __restrict__ temp, float* __restrict__ out,
    float* __restrict__ imp_part, float* __restrict__ load_part,
    float* __restrict__ ent_part, float* __restrict__ imp2,
    float* __restrict__ load2, float* __restrict__ ent2,
    u32* __restrict__ tickets) {
  __shared__ float lds[16384];   // 64 KB: 4 bufs x 32 rows x 128 floats
  const int tid  = threadIdx.x;
  const int w    = tid >> 6;
  const int lane = tid & 63;
  const int t0   = blockIdx.x * 32;
  const int rl   = lane & 31;
  const int hg   = lane >> 5;

  float tv = temp[0];
  tv = fminf(fmaxf(tv, 0.1f), 5.0f);
  const float invT = 1.0f / tv;

  // glds source bases (i=0,1): rows r0=w*4+i*2; lane covers row r0+hg,
  // physical chunk (lane&31) holds logical chunk (lane&31)^row.
  const float* gsrc[2];
#pragma unroll
  for (int i = 0; i < 2; ++i) {
    int r0  = w * 4 + i * 2;
    int row = r0 + hg;
    int sc  = rl ^ (row & 31);
    gsrc[i] = x + (size_t)(t0 + row) * D_MODEL + sc * 4;
  }

  auto stage = [&](int st) {
    const int buf = st & 3;
#pragma unroll
    for (int i = 0; i < 2; ++i) {
      int r0 = w * 4 + i * 2;             // wave-uniform dest base
      __builtin_amdgcn_global_load_lds(
          (const __attribute__((address_space(1))) void*)(gsrc[i] + st * 128),
          (__attribute__((address_space(3))) void*)(lds + buf * 4096 + r0 * 128),
          16, 0, 0);
    }
  };
  auto loadB = [&](int st, bf16x8* bb) {
    const bf16x8* wp = Wf + (size_t)(st * 8 + w) * 128 + lane;
#pragma unroll
    for (int p = 0; p < 3; ++p)
#pragma unroll
      for (int n = 0; n < 2; ++n)
        bb[p * 2 + n] = wp[p * WF_PS + n * 64];
  };

  f32x16 acc0, acc1;
#pragma unroll
  for (int i = 0; i < 16; ++i) { acc0[i] = 0.0f; acc1[i] = 0.0f; }

  bf16x8 b[2][6];
  stage(0); stage(1);            // 4 glds in flight
  loadB(0, b[0]);                // 6 B-loads
  // S0 retired when newer-than-S0 (S1:2 + B0:6 = 8) are the only outstanding
  asm volatile("s_waitcnt vmcnt(8)" ::: "memory");
  FULLBAR();

  const int c0 = w * 4 + hg * 2;         // logical 16B-chunk of this lane

#pragma unroll
  for (int st = 0; st < NSTG; ++st) {
    if (st + 1 < NSTG) loadB(st + 1, b[(st + 1) & 1]);
    if (st + 2 < NSTG) stage(st + 2);

    const float* rb = lds + (st & 3) * 4096 + rl * 128;
    float4 a0 = *(const float4*)(rb + ((c0 ^ rl) << 2));
    float4 a1 = *(const float4*)(rb + (((c0 + 1) ^ rl) << 2));
    float av[8] = {a0.x, a0.y, a0.z, a0.w, a1.x, a1.y, a1.z, a1.w};
    bf16x8 ah, am, al;
#pragma unroll
    for (int j = 0; j < 8; ++j) {
      u32 hh, mm, ll;
      split3(av[j], hh, mm, ll);
      ah[j] = (short)hh; am[j] = (short)mm; al[j] = (short)ll;
    }
    const bf16x8* bb = b[st & 1];
    acc0 = __builtin_amdgcn_mfma_f32_32x32x16_bf16(ah, bb[0], acc0, 0, 0, 0);
    acc1 = __builtin_amdgcn_mfma_f32_32x32x16_bf16(ah, bb[1], acc1, 0, 0, 0);
    acc0 = __builtin_amdgcn_mfma_f32_32x32x16_bf16(ah, bb[2], acc0, 0, 0, 0);
    acc1 = __builtin_amdgcn_mfma_f32_32x32x16_bf16(ah, bb[3], acc1, 0, 0, 0);
    acc0 = __builtin_amdgcn_mfma_f32_32x32x16_bf16(am, bb[0], acc0, 0, 0, 0);
    acc1 = __builtin_amdgcn_mfma_f32_32x32x16_bf16(am, bb[1], acc1, 0, 0, 0);
    acc0 = __builtin_amdgcn_mfma_f32_32x32x16_bf16(am, bb[2], acc0, 0, 0, 0);
    acc1 = __builtin_amdgcn_mfma_f32_32x32x16_bf16(am, bb[3], acc1, 0, 0, 0);
    acc0 = __builtin_amdgcn_mfma_f32_32x32x16_bf16(ah, bb[4], acc0, 0, 0, 0);
    acc1 = __builtin_amdgcn_mfma_f32_32x32x16_bf16(ah, bb[5], acc1, 0, 0, 0);
    acc0 = __builtin_amdgcn_mfma_f32_32x32x16_bf16(al, bb[0], acc0, 0, 0, 0);
    acc1 = __builtin_amdgcn_mfma_f32_32x32x16_bf16(al, bb[1], acc1, 0, 0, 0);

    // end-of-stage: S(st+1) retired iff newest 8 (B(st+1):6 + S(st+2):2)
    // are the only outstanding. Tail st=14: only B15:6 newer -> vmcnt(6).
    if (st < NSTG - 2) {
      asm volatile("s_waitcnt vmcnt(8)" ::: "memory");
      FULLBAR();
    } else if (st == NSTG - 2) {
      asm volatile("s_waitcnt vmcnt(6)" ::: "memory");
      FULLBAR();
    }
  }

  // ---- epilogue: 8-way K reduction in LDS (verified r7/r8) ----
  __syncthreads();
#pragma unroll
  for (int r = 0; r < 16; ++r) {
    int row = (r & 3) + ((r >> 2) << 3) + (hg << 2);
    lds[w * 2048 + row * 64 + rl]      = acc0[r];
    lds[w * 2048 + row * 64 + 32 + rl] = acc1[r];
  }
  __syncthreads();

  const int row  = tid >> 4;         // 0..31 token row
  const int colq = tid & 15;         // 16B expert chunk
  float l0 = 0.f, l1 = 0.f, l2 = 0.f, l3 = 0.f;
  for (int wv = 0; wv < 8; ++wv) {   // ascending: deterministic
    float4 v = *(const float4*)&lds[wv * 2048 + row * 64 + colq * 4];
    l0 += v.x; l1 += v.y; l2 += v.z; l3 += v.w;
  }
  l0 *= invT; l1 *= invT; l2 *= invT; l3 *= invT;

  float m = fmaxf(fmaxf(l0, l1), fmaxf(l2, l3));
#pragma unroll
  for (int d = 1; d < 16; d <<= 1) m = fmaxf(m, __shfl_xor(m, d));

  float ls0 = l0 - m, ls1 = l1 - m, ls2 = l2 - m, ls3 = l3 - m;
  float e0 = __expf(ls0), e1 = __expf(ls1), e2 = __expf(ls2), e3 = __expf(ls3);
  float ssum = e0 + e1 + e2 + e3;
  float dot  = e0 * ls0 + e1 * ls1 + e2 * ls2 + e3 * ls3;
#pragma unroll
  for (int d = 1; d < 16; d <<= 1) {
    ssum += __shfl_xor(ssum, d);
    dot  += __shfl_xor(dot, d);
  }
  const float inv_s = 1.0f / ssum;
  const float ent = __logf(ssum) - dot * inv_s;   // -sum p log p

  const int eb = colq * 4;
  float b1 = e0, b2 = -1.0f;
  int   i1 = eb, i2 = eb + 1;
  {
    float ev[3] = {e1, e2, e3};
#pragma unroll
    for (int j = 0; j < 3; ++j) {
      int ej = eb + 1 + j;
      if (better(ev[j], ej, b1, i1)) { b2 = b1; i2 = i1; b1 = ev[j]; i1 = ej; }
      else if (better(ev[j], ej, b2, i2)) { b2 = ev[j]; i2 = ej; }
    }
  }
#pragma unroll
  for (int d = 1; d < 16; d <<= 1) {
    float ob1 = __shfl_xor(b1, d), ob2 = __shfl_xor(b2, d);
    int   oi1 = __shfl_xor(i1, d), oi2 = __shfl_xor(i2, d);
    if (better(ob1, oi1, b1, i1)) {
      if (better(b1, i1, ob2, oi2)) { b2 = b1; i2 = i1; }
      else                          { b2 = ob2; i2 = oi2; }
      b1 = ob1; i1 = oi1;
    } else if (better(ob1, oi1, b2, i2)) {
      b2 = ob1; i2 = oi1;
    }
  }

  const int t = t0 + row;
  if (colq == 0) {
    out[OFF_PROBS + (size_t)t * 2 + 0] = b1 * inv_s;
    out[OFF_PROBS + (size_t)t * 2 + 1] = b2 * inv_s;
    out[OFF_IDX   + (size_t)t * 2 + 0] = (float)i1;
    out[OFF_IDX   + (size_t)t * 2 + 1] = (float)i2;
  }
  {
    float4 mv;
    mv.x = ((eb + 0 == i1) || (eb + 0 == i2)) ? 1.0f : 0.0f;
    mv.y = ((eb + 1 == i1) || (eb + 1 == i2)) ? 1.0f : 0.0f;
    mv.z = ((eb + 2 == i1) || (eb + 2 == i2)) ? 1.0f : 0.0f;
    mv.w = ((eb + 3 == i1) || (eb + 3 == i2)) ? 1.0f : 0.0f;
    *(float4*)&out[OFF_MASK + (size_t)t * N_EXP + eb] = mv;
  }

  // ---- block aux partials (deterministic fixed order) ----
  __syncthreads();
  {
    float4 p4;
    p4.x = e0 * inv_s; p4.y = e1 * inv_s; p4.z = e2 * inv_s; p4.w = e3 * inv_s;
    *(float4*)&lds[row * 64 + eb] = p4;
  }
  if (colq == 0) {
    lds[2048 + row] = (float)i1;
    lds[2080 + row] = (float)i2;
    lds[2112 + row] = ent;
  }
  __syncthreads();
  if (tid < 64) {
    float simp = 0.0f, sld = 0.0f;
    const float fe = (float)tid;
    for (int r = 0; r < 32; ++r) simp += lds[r * 64 + tid];
    for (int r = 0; r < 32; ++r)
      sld += ((lds[2048 + r] == fe) ? 1.0f : 0.0f)
           + ((lds[2080 + r] == fe) ? 1.0f : 0.0f);
    imp_part[blockIdx.x * N_EXP + tid]  = simp;
    load_part[blockIdx.x * N_EXP + tid] = sld;
    float v = (tid < 32) ? lds[2112 + tid] : 0.0f;
#pragma unroll
    for (int d = 1; d < 64; d <<= 1) v += __shfl_xor(v, d);
    if (tid == 0) ent_part[blockIdx.x] = v;
  }

  // ---- r14: in-kernel finalize (two-level ticket; replaces 2 dispatches) --
  // Level 1: 8 consecutive blocks per group (matches old finalize_part
  // mapping); 8th arrival reduces the group with the IDENTICAL pairwise tree.
  // Level 2: 64th group-leader replicates finalize_final verbatim.
  // Cross-XCD visibility: release = __threadfence before ticket (L2
  // writeback); acquire = __threadfence after winning ticket (L2/L1 inv).
  __syncthreads();                       // drain this block's partial stores
  const int g = blockIdx.x >> 3;
  if (tid == 0) {
    __threadfence();                     // release partials to device scope
    u32 old = atomicAdd(&tickets[g], 1u);
    lds[0] = (float)old;                 // block-uniform broadcast
  }
  __syncthreads();
  if ((int)lds[0] == 7) {                // group leader (block-uniform branch)
    __threadfence();                     // acquire: invalidate stale caches
    const int b0 = g * 8;
    if (tid < 64) {
      // replicate finalize_part: ((s01+s23)+s45)+s67, sXY = pX + pY
      float i01 = imp_part[(size_t)(b0+0)*N_EXP+tid] + imp_part[(size_t)(b0+1)*N_EXP+tid];
      float i23 = imp_part[(size_t)(b0+2)*N_EXP+tid] + imp_part[(size_t)(b0+3)*N_EXP+tid];
      float i45 = imp_part[(size_t)(b0+4)*N_EXP+tid] + imp_part[(size_t)(b0+5)*N_EXP+tid];
      float i67 = imp_part[(size_t)(b0+6)*N_EXP+tid] + imp_part[(size_t)(b0+7)*N_EXP+tid];
      imp2[g * N_EXP + tid] = ((i01 + i23) + i45) + i67;
      float d01 = load_part[(size_t)(b0+0)*N_EXP+tid] + load_part[(size_t)(b0+1)*N_EXP+tid];
      float d23 = load_part[(size_t)(b0+2)*N_EXP+tid] + load_part[(size_t)(b0+3)*N_EXP+tid];
      float d45 = load_part[(size_t)(b0+4)*N_EXP+tid] + load_part[(size_t)(b0+5)*N_EXP+tid];
      float d67 = load_part[(size_t)(b0+6)*N_EXP+tid] + load_part[(size_t)(b0+7)*N_EXP+tid];
      load2[g * N_EXP + tid] = ((d01 + d23) + d45) + d67;
      if (tid == 0) {
        float e01 = ent_part[b0+0] + ent_part[b0+1];
        float e23 = ent_part[b0+2] + ent_part[b0+3];
        float e45 = ent_part[b0+4] + ent_part[b0+5];
        float e67 = ent_part[b0+6] + ent_part[b0+7];
        ent2[g] = ((e01 + e23) + e45) + e67;
      }
    }
    __syncthreads();                     // drain leader's level-2 stores
    if (tid == 0) {
      __threadfence();                   // release level-2
      u32 fo = atomicAdd(&tickets[64], 1u);
      lds[0] = (float)fo;
    }
    __syncthreads();
    if ((int)lds[0] == 63) {             // final leader (block-uniform)
      __threadfence();                   // acquire level-2
      // replicate finalize_final verbatim (256 active threads)
      if (tid < 256) {
        const int q = tid >> 6, ln = tid & 63;
        float a = 0.0f, bql = 0.0f;
        for (int r = q * 16; r < q * 16 + 16; ++r) {   // ascending
          a   += imp2[r * N_EXP + ln];
          bql += load2[r * N_EXP + ln];
        }
        lds[q * 64 + ln]       = a;      // si[q][ln]
        lds[256 + q * 64 + ln] = bql;    // sl[q][ln]
      }
      __syncthreads();
      if (tid < 64) {
        float imp = lds[tid] + lds[64 + tid] + lds[128 + tid] + lds[192 + tid];
        float ld  = lds[256 + tid] + lds[320 + tid] + lds[384 + tid] + lds[448 + tid];
        imp *= (1.0f / 16384.0f);
        ld  *= (1.0f / (16384.0f + 1e-6f));
        float prod = imp * ld;
        float e = ent2[tid];
#pragma unroll
        for (int d = 1; d < 64; d <<= 1) {
          prod += __shfl_xor(prod, d);
          e    += __shfl_xor(e, d);
        }
        if (tid == 0) {
          out[OFF_AUX] = prod * 64.0f * 0.01f;
          out[OFF_ENT] = (e / 16384.0f) * 0.01f;
        }
      }
    }
  }
}

extern "C" void kernel_launch(void* const* d_in, const int* in_sizes, int n_in,
                              void* d_out, int out_size, void* d_ws, size_t ws_size,
                              hipStream_t stream) {
  const float* x    = (const float*)d_in[0];
  const float* W    = (const float*)d_in[1];
  const float* temp = (const float*)d_in[2];
  float* out = (float*)d_out;
  float* ws  = (float*)d_ws;

  // ws floats: Wf 196608 | imp 32768 | load 32768 | ent 512 | imp2 4096 |
  //            load2 4096 | ent2 64 | tickets (65 u32)
  bf16x8* Wf    = (bf16x8*)ws;
  float*  imp   = ws + 196608;
  float*  ldp   = imp + NBLK * N_EXP;
  float*  entp  = ldp + NBLK * N_EXP;
  float*  imp2  = entp + NBLK;
  float*  load2 = imp2 + 64 * N_EXP;
  float*  ent2  = load2 + 64 * N_EXP;
  u32*    tick  = (u32*)(ent2 + 64);

  wprep_kernel<<<64, 256, 0, stream>>>(W, Wf, tick);
  fused_kernel<<<NBLK, 512, 0, stream>>>(x, Wf, temp, out, imp, ldp, entp,
                                         imp2, load2, ent2, tick);
}

// Round 6
// 55.610 us; speedup vs baseline: 2.2868x; 2.2868x over previous
//
#include <hip/hip_runtime.h>
#include <hip/hip_bf16.h>
#include <math.h>

#define D_MODEL 2048
#define N_EXP   64
#define NTOK    16384           // 4 * 4096
#define NBLK    512             // NTOK / 32 tokens per block
#define NSTG    16              // K stages: 2048 / 128

typedef short bf16x8 __attribute__((ext_vector_type(8)));
typedef float f32x16 __attribute__((ext_vector_type(16)));
typedef unsigned int u32;

// out layout (floats)
#define OFF_PROBS 0
#define OFF_IDX   32768
#define OFF_MASK  65536
#define OFF_AUX   1114112
#define OFF_ENT   1114113

#define WF_PS 16384            // bf16x8 units per split-part (128 g * 2 n * 64)

#define MEMFENCE asm volatile("" ::: "memory")
// fence + barrier + fence: s_barrier alone is NOT a compiler memory fence;
// without the trailing fence the compiler may hoist next-stage LDS reads
// above the barrier (r9 failure: cross-wave stage rows read stale).
#define FULLBAR() do { MEMFENCE; __builtin_amdgcn_s_barrier(); MEMFENCE; \
                       __builtin_amdgcn_sched_barrier(0); } while (0)

__device__ __forceinline__ void split3(float xv, u32& h, u32& m, u32& l) {
  u32 xb = __builtin_bit_cast(u32, xv);
  u32 hb = xb & 0xFFFF0000u;
  float tf = xv - __builtin_bit_cast(float, hb);      // exact (Sterbenz)
  u32 tb = __builtin_bit_cast(u32, tf);
  u32 mb = tb & 0xFFFF0000u;
  float t2 = tf - __builtin_bit_cast(float, mb);      // exact; bf16-representable
  u32 lb = __builtin_bit_cast(u32, t2);
  h = hb >> 16; m = mb >> 16; l = lb >> 16;
}

__device__ __forceinline__ bool better(float a, int ia, float b, int ib) {
  return (a > b) || (a == b && ia < ib);
}

// W[64][2048] -> 3 bf16 parts in 32x32x16 B-fragment order. (verified r5-r8)
__global__ __launch_bounds__(256) void wprep_kernel(
    const float* __restrict__ W, bf16x8* __restrict__ Wf) {
  int gid  = blockIdx.x * 256 + threadIdx.x;   // 16384
  int g    = gid >> 7;
  int n    = (gid >> 6) & 1;
  int lane = gid & 63;
  int e    = n * 32 + (lane & 31);
  int k    = g * 16 + ((lane >> 5) << 3);
  const float* wr = W + (size_t)e * D_MODEL + k;
  bf16x8 hv, mv, lv;
#pragma unroll
  for (int j = 0; j < 8; ++j) {
    u32 h, m, l;
    split3(wr[j], h, m, l);
    hv[j] = (short)h; mv[j] = (short)m; lv[j] = (short)l;
  }
  Wf[gid]             = hv;
  Wf[WF_PS + gid]     = mv;
  Wf[2 * WF_PS + gid] = lv;
}

// r15: r12 structure (50.8us verified best) + DEPTH-3 prefetch.
// r14 post-mortem: in-kernel finalize w/ per-block __threadfence (L2
// writeback/inv x512 blocks at staggered times) destroyed cache behavior
// (fused 185us @ 410GB/s). Reverted to 4 dispatches.
// r14's counters gave the first real data: VGPR=60, LDS=64KB -> 2 blocks/CU.
// Little's law: depth-2 keeps 4KB/block in flight; 2 blocks = 8KB/CU vs
// ~12.3KB needed (24.6 GB/s/CU x ~500ns) -> ~65% BW -> matches observed
// ~3.3 TB/s. Fix: depth-3 prefetch on the SAME 4 buffers (max legal depth:
// bufs st+1..st+3 pending + st read). stage(st+3) writes buf (st-1)&3 whose
// readers all passed the end-of-(st-1) FULLBAR -> safe. 6KB/block in flight
// -> 12KB/CU ~= Little's-law requirement.
// vmcnt ledger (loadB first, then stage -- r10 lesson):
//   prologue: S0,S1,S2 (6 glds) + B0:6 -> S0 retired iff newest 10
//   (S1:2+S2:2+B0:6) are the only outstanding -> vmcnt(10).
//   iter st<=12: newer-than-S(st+1) that may be outstanding:
//   S(st+2):2 + B(st+1):6 + S(st+3):2 = 10 -> vmcnt(10).
//   st=13: S(15):2 + B(14):6 = 8 -> vmcnt(8). st=14: B(15):6 -> vmcnt(6).
// Reads, MFMA order, epilogue, finalize: bit-identical to r12.
__global__ __launch_bounds__(512, 4) void fused_kernel(
    const float* __restrict__ x, const bf16x8* __restrict__ Wf,
    const float* __restrict__ temp, float* __restrict__ out,
    float* __restrict__ imp_part, float* __restrict__ load_part,
    float* __restrict__ ent_part) {
  __shared__ float lds[16384];   // 64 KB: 4 bufs x 32 rows x 128 floats
  const int tid  = threadIdx.x;
  const int w    = tid >> 6;
  const int lane = tid & 63;
  const int t0   = blockIdx.x * 32;
  const int rl   = lane & 31;
  const int hg   = lane >> 5;

  float tv = temp[0];
  tv = fminf(fmaxf(tv, 0.1f), 5.0f);
  const float invT = 1.0f / tv;

  // glds source bases (i=0,1): rows r0=w*4+i*2; lane covers row r0+hg,
  // physical chunk (lane&31) holds logical chunk (lane&31)^row.
  const float* gsrc[2];
#pragma unroll
  for (int i = 0; i < 2; ++i) {
    int r0  = w * 4 + i * 2;
    int row = r0 + hg;
    int sc  = rl ^ (row & 31);
    gsrc[i] = x + (size_t)(t0 + row) * D_MODEL + sc * 4;
  }

  auto stage = [&](int st) {
    const int buf = st & 3;
#pragma unroll
    for (int i = 0; i < 2; ++i) {
      int r0 = w * 4 + i * 2;             // wave-uniform dest base
      __builtin_amdgcn_global_load_lds(
          (const __attribute__((address_space(1))) void*)(gsrc[i] + st * 128),
          (__attribute__((address_space(3))) void*)(lds + buf * 4096 + r0 * 128),
          16, 0, 0);
    }
  };
  auto loadB = [&](int st, bf16x8* bb) {
    const bf16x8* wp = Wf + (size_t)(st * 8 + w) * 128 + lane;
#pragma unroll
    for (int p = 0; p < 3; ++p)
#pragma unroll
      for (int n = 0; n < 2; ++n)
        bb[p * 2 + n] = wp[p * WF_PS + n * 64];
  };

  f32x16 acc0, acc1;
#pragma unroll
  for (int i = 0; i < 16; ++i) { acc0[i] = 0.0f; acc1[i] = 0.0f; }

  bf16x8 b[2][6];
  stage(0); stage(1); stage(2);  // 6 glds in flight (depth 3)
  loadB(0, b[0]);                // 6 B-loads
  // S0 retired when newest 10 (S1:2 + S2:2 + B0:6) are the only outstanding
  asm volatile("s_waitcnt vmcnt(10)" ::: "memory");
  FULLBAR();

  const int c0 = w * 4 + hg * 2;         // logical 16B-chunk of this lane

#pragma unroll
  for (int st = 0; st < NSTG; ++st) {
    if (st + 1 < NSTG) loadB(st + 1, b[(st + 1) & 1]);
    if (st + 3 < NSTG) stage(st + 3);

    const float* rb = lds + (st & 3) * 4096 + rl * 128;
    float4 a0 = *(const float4*)(rb + ((c0 ^ rl) << 2));
    float4 a1 = *(const float4*)(rb + (((c0 + 1) ^ rl) << 2));
    float av[8] = {a0.x, a0.y, a0.z, a0.w, a1.x, a1.y, a1.z, a1.w};
    bf16x8 ah, am, al;
#pragma unroll
    for (int j = 0; j < 8; ++j) {
      u32 hh, mm, ll;
      split3(av[j], hh, mm, ll);
      ah[j] = (short)hh; am[j] = (short)mm; al[j] = (short)ll;
    }
    const bf16x8* bb = b[st & 1];
    acc0 = __builtin_amdgcn_mfma_f32_32x32x16_bf16(ah, bb[0], acc0, 0, 0, 0);
    acc1 = __builtin_amdgcn_mfma_f32_32x32x16_bf16(ah, bb[1], acc1, 0, 0, 0);
    acc0 = __builtin_amdgcn_mfma_f32_32x32x16_bf16(ah, bb[2], acc0, 0, 0, 0);
    acc1 = __builtin_amdgcn_mfma_f32_32x32x16_bf16(ah, bb[3], acc1, 0, 0, 0);
    acc0 = __builtin_amdgcn_mfma_f32_32x32x16_bf16(am, bb[0], acc0, 0, 0, 0);
    acc1 = __builtin_amdgcn_mfma_f32_32x32x16_bf16(am, bb[1], acc1, 0, 0, 0);
    acc0 = __builtin_amdgcn_mfma_f32_32x32x16_bf16(am, bb[2], acc0, 0, 0, 0);
    acc1 = __builtin_amdgcn_mfma_f32_32x32x16_bf16(am, bb[3], acc1, 0, 0, 0);
    acc0 = __builtin_amdgcn_mfma_f32_32x32x16_bf16(ah, bb[4], acc0, 0, 0, 0);
    acc1 = __builtin_amdgcn_mfma_f32_32x32x16_bf16(ah, bb[5], acc1, 0, 0, 0);
    acc0 = __builtin_amdgcn_mfma_f32_32x32x16_bf16(al, bb[0], acc0, 0, 0, 0);
    acc1 = __builtin_amdgcn_mfma_f32_32x32x16_bf16(al, bb[1], acc1, 0, 0, 0);

    // end-of-stage: need S(st+1) retired before next iteration's reads.
    if (st <= NSTG - 4) {                // st <= 12
      asm volatile("s_waitcnt vmcnt(10)" ::: "memory");
      FULLBAR();
    } else if (st == NSTG - 3) {         // st == 13
      asm volatile("s_waitcnt vmcnt(8)" ::: "memory");
      FULLBAR();
    } else if (st == NSTG - 2) {         // st == 14
      asm volatile("s_waitcnt vmcnt(6)" ::: "memory");
      FULLBAR();
    }
  }

  // ---- epilogue: 8-way K reduction in LDS (verified r7/r8) ----
  __syncthreads();
#pragma unroll
  for (int r = 0; r < 16; ++r) {
    int row = (r & 3) + ((r >> 2) << 3) + (hg << 2);
    lds[w * 2048 + row * 64 + rl]      = acc0[r];
    lds[w * 2048 + row * 64 + 32 + rl] = acc1[r];
  }
  __syncthreads();

  const int row  = tid >> 4;         // 0..31 token row
  const int colq = tid & 15;         // 16B expert chunk
  float l0 = 0.f, l1 = 0.f, l2 = 0.f, l3 = 0.f;
  for (int wv = 0; wv < 8; ++wv) {   // ascending: deterministic
    float4 v = *(const float4*)&lds[wv * 2048 + row * 64 + colq * 4];
    l0 += v.x; l1 += v.y; l2 += v.z; l3 += v.w;
  }
  l0 *= invT; l1 *= invT; l2 *= invT; l3 *= invT;

  float m = fmaxf(fmaxf(l0, l1), fmaxf(l2, l3));
#pragma unroll
  for (int d = 1; d < 16; d <<= 1) m = fmaxf(m, __shfl_xor(m, d));

  float ls0 = l0 - m, ls1 = l1 - m, ls2 = l2 - m, ls3 = l3 - m;
  float e0 = __expf(ls0), e1 = __expf(ls1), e2 = __expf(ls2), e3 = __expf(ls3);
  float ssum = e0 + e1 + e2 + e3;
  float dot  = e0 * ls0 + e1 * ls1 + e2 * ls2 + e3 * ls3;
#pragma unroll
  for (int d = 1; d < 16; d <<= 1) {
    ssum += __shfl_xor(ssum, d);
    dot  += __shfl_xor(dot, d);
  }
  const float inv_s = 1.0f / ssum;
  const float ent = __logf(ssum) - dot * inv_s;   // -sum p log p

  const int eb = colq * 4;
  float b1 = e0, b2 = -1.0f;
  int   i1 = eb, i2 = eb + 1;
  {
    float ev[3] = {e1, e2, e3};
#pragma unroll
    for (int j = 0; j < 3; ++j) {
      int ej = eb + 1 + j;
      if (better(ev[j], ej, b1, i1)) { b2 = b1; i2 = i1; b1 = ev[j]; i1 = ej; }
      else if (better(ev[j], ej, b2, i2)) { b2 = ev[j]; i2 = ej; }
    }
  }
#pragma unroll
  for (int d = 1; d < 16; d <<= 1) {
    float ob1 = __shfl_xor(b1, d), ob2 = __shfl_xor(b2, d);
    int   oi1 = __shfl_xor(i1, d), oi2 = __shfl_xor(i2, d);
    if (better(ob1, oi1, b1, i1)) {
      if (better(b1, i1, ob2, oi2)) { b2 = b1; i2 = i1; }
      else                          { b2 = ob2; i2 = oi2; }
      b1 = ob1; i1 = oi1;
    } else if (better(ob1, oi1, b2, i2)) {
      b2 = ob1; i2 = oi1;
    }
  }

  const int t = t0 + row;
  if (colq == 0) {
    out[OFF_PROBS + (size_t)t * 2 + 0] = b1 * inv_s;
    out[OFF_PROBS + (size_t)t * 2 + 1] = b2 * inv_s;
    out[OFF_IDX   + (size_t)t * 2 + 0] = (float)i1;
    out[OFF_IDX   + (size_t)t * 2 + 1] = (float)i2;
  }
  {
    float4 mv;
    mv.x = ((eb + 0 == i1) || (eb + 0 == i2)) ? 1.0f : 0.0f;
    mv.y = ((eb + 1 == i1) || (eb + 1 == i2)) ? 1.0f : 0.0f;
    mv.z = ((eb + 2 == i1) || (eb + 2 == i2)) ? 1.0f : 0.0f;
    mv.w = ((eb + 3 == i1) || (eb + 3 == i2)) ? 1.0f : 0.0f;
    *(float4*)&out[OFF_MASK + (size_t)t * N_EXP + eb] = mv;
  }

  // ---- block aux partials (deterministic fixed order) ----
  __syncthreads();
  {
    float4 p4;
    p4.x = e0 * inv_s; p4.y = e1 * inv_s; p4.z = e2 * inv_s; p4.w = e3 * inv_s;
    *(float4*)&lds[row * 64 + eb] = p4;
  }
  if (colq == 0) {
    lds[2048 + row] = (float)i1;
    lds[2080 + row] = (float)i2;
    lds[2112 + row] = ent;
  }
  __syncthreads();
  if (tid < 64) {
    float simp = 0.0f, sld = 0.0f;
    const float fe = (float)tid;
    for (int r = 0; r < 32; ++r) simp += lds[r * 64 + tid];
    for (int r = 0; r < 32; ++r)
      sld += ((lds[2048 + r] == fe) ? 1.0f : 0.0f)
           + ((lds[2080 + r] == fe) ? 1.0f : 0.0f);
    imp_part[blockIdx.x * N_EXP + tid]  = simp;
    load_part[blockIdx.x * N_EXP + tid] = sld;
    float v = (tid < 32) ? lds[2112 + tid] : 0.0f;
#pragma unroll
    for (int d = 1; d < 64; d <<= 1) v += __shfl_xor(v, d);
    if (tid == 0) ent_part[blockIdx.x] = v;
  }
}

// Finalize split (validated r11/r12, absmax unchanged): parallel partial
// reduce (64 blocks) + single-block final. Fixed order -> deterministic.
__global__ __launch_bounds__(256) void finalize_part(
    const float* __restrict__ imp_part, const float* __restrict__ load_part,
    const float* __restrict__ ent_part, float* __restrict__ imp2,
    float* __restrict__ load2, float* __restrict__ ent2) {
  __shared__ float si[4][64], sl[4][64], se[4];
  const int tid  = threadIdx.x;
  const int lane = tid & 63;
  const int q    = tid >> 6;
  const int base = blockIdx.x * 8 + q * 2;     // 2 source blocks per quarter
  float a = imp_part[(size_t)base * N_EXP + lane]
          + imp_part[(size_t)(base + 1) * N_EXP + lane];
  float b = load_part[(size_t)base * N_EXP + lane]
          + load_part[(size_t)(base + 1) * N_EXP + lane];
  si[q][lane] = a;
  sl[q][lane] = b;
  if (lane == 0) se[q] = ent_part[base] + ent_part[base + 1];
  __syncthreads();
  if (tid < 64) {
    imp2[blockIdx.x * N_EXP + tid]  = si[0][tid] + si[1][tid] + si[2][tid] + si[3][tid];
    load2[blockIdx.x * N_EXP + tid] = sl[0][tid] + sl[1][tid] + sl[2][tid] + sl[3][tid];
    if (tid == 0) ent2[blockIdx.x] = se[0] + se[1] + se[2] + se[3];
  }
}

__global__ __launch_bounds__(256) void finalize_final(
    const float* __restrict__ imp2, const float* __restrict__ load2,
    const float* __restrict__ ent2, float* __restrict__ out) {
  __shared__ float si[4][64], sl[4][64];
  const int tid  = threadIdx.x;
  const int lane = tid & 63;
  const int q    = tid >> 6;
  float a = 0.0f, b = 0.0f;
  for (int r = q * 16; r < q * 16 + 16; ++r) {   // ascending: deterministic
    a += imp2[r * N_EXP + lane];
    b += load2[r * N_EXP + lane];
  }
  si[q][lane] = a;
  sl[q][lane] = b;
  __syncthreads();
  if (tid < 64) {
    float imp = si[0][tid] + si[1][tid] + si[2][tid] + si[3][tid];
    float ld  = sl[0][tid] + sl[1][tid] + sl[2][tid] + sl[3][tid];
    imp *= (1.0f / 16384.0f);
    ld  *= (1.0f / (16384.0f + 1e-6f));
    float prod = imp * ld;
    float e = ent2[tid];
#pragma unroll
    for (int d = 1; d < 64; d <<= 1) {
      prod += __shfl_xor(prod, d);
      e    += __shfl_xor(e, d);
    }
    if (tid == 0) {
      out[OFF_AUX] = prod * 64.0f * 0.01f;
      out[OFF_ENT] = (e / 16384.0f) * 0.01f;
    }
  }
}

extern "C" void kernel_launch(void* const* d_in, const int* in_sizes, int n_in,
                              void* d_out, int out_size, void* d_ws, size_t ws_size,
                              hipStream_t stream) {
  const float* x    = (const float*)d_in[0];
  const float* W    = (const float*)d_in[1];
  const float* temp = (const float*)d_in[2];
  float* out = (float*)d_out;
  float* ws  = (float*)d_ws;

  // ws floats: Wf 196608 | imp 32768 | load 32768 | ent 512 | imp2 4096 |
  //            load2 4096 | ent2 64
  bf16x8* Wf    = (bf16x8*)ws;
  float*  imp   = ws + 196608;
  float*  ldp   = imp + NBLK * N_EXP;
  float*  entp  = ldp + NBLK * N_EXP;
  float*  imp2  = entp + NBLK;
  float*  load2 = imp2 + 64 * N_EXP;
  float*  ent2  = load2 + 64 * N_EXP;

  wprep_kernel<<<64, 256, 0, stream>>>(W, Wf);
  fused_kernel<<<NBLK, 512, 0, stream>>>(x, Wf, temp, out, imp, ldp, entp);
  finalize_part<<<64, 256, 0, stream>>>(imp, ldp, entp, imp2, load2, ent2);
  finalize_final<<<1, 256, 0, stream>>>(imp2, load2, ent2, out);
}

// Round 7
// 54.957 us; speedup vs baseline: 2.3140x; 1.0119x over previous
//
#include <hip/hip_runtime.h>
#include <hip/hip_bf16.h>
#include <math.h>

#define D_MODEL 2048
#define N_EXP   64
#define NTOK    16384           // 4 * 4096
#define NBLK    512             // NTOK / 32 tokens per block
#define NSTG    16              // K stages: 2048 / 128

typedef short bf16x8 __attribute__((ext_vector_type(8)));
typedef float f32x16 __attribute__((ext_vector_type(16)));
typedef unsigned int u32;

// out layout (floats)
#define OFF_PROBS 0
#define OFF_IDX   32768
#define OFF_MASK  65536
#define OFF_AUX   1114112
#define OFF_ENT   1114113

#define WF_PS 16384            // bf16x8 units per split-part (128 g * 2 n * 64)

__device__ __forceinline__ void split3(float xv, u32& h, u32& m, u32& l) {
  u32 xb = __builtin_bit_cast(u32, xv);
  u32 hb = xb & 0xFFFF0000u;
  float tf = xv - __builtin_bit_cast(float, hb);      // exact (Sterbenz)
  u32 tb = __builtin_bit_cast(u32, tf);
  u32 mb = tb & 0xFFFF0000u;
  float t2 = tf - __builtin_bit_cast(float, mb);      // exact; bf16-representable
  u32 lb = __builtin_bit_cast(u32, t2);
  h = hb >> 16; m = mb >> 16; l = lb >> 16;
}

__device__ __forceinline__ bool better(float a, int ia, float b, int ib) {
  return (a > b) || (a == b && ia < ib);
}

// W[64][2048] -> 3 bf16 parts in 32x32x16 B-fragment order. (verified r5-r8)
__global__ __launch_bounds__(256) void wprep_kernel(
    const float* __restrict__ W, bf16x8* __restrict__ Wf) {
  int gid  = blockIdx.x * 256 + threadIdx.x;   // 16384
  int g    = gid >> 7;
  int n    = (gid >> 6) & 1;
  int lane = gid & 63;
  int e    = n * 32 + (lane & 31);
  int k    = g * 16 + ((lane >> 5) << 3);
  const float* wr = W + (size_t)e * D_MODEL + k;
  bf16x8 hv, mv, lv;
#pragma unroll
  for (int j = 0; j < 8; ++j) {
    u32 h, m, l;
    split3(wr[j], h, m, l);
    hv[j] = (short)h; mv[j] = (short)m; lv[j] = (short)l;
  }
  Wf[gid]             = hv;
  Wf[WF_PS + gid]     = mv;
  Wf[2 * WF_PS + gid] = lv;
}

// r16: REGISTER-DIRECT A path -- no staging LDS, no main-loop barriers.
// r15 post-mortem: vmcnt is ONE in-order queue; per-stage B-loads act as
// implicit drain points, capping glds stage-prefetch at ~2 regardless of
// issue depth (r10/r11/r15 all hit this). Deeper diagnosis: barrier-synced
// burst issue leaves the memory pipe idle most of each stage (avg in-flight
// ~3-8KB/CU < 12.3KB Little's-law need -> ~3.3TB/s delivered). The 6.3TB/s
// copy ubench has NO barriers: waves stream independently.
// Fix: each wave loads its OWN A-fragment straight to VGPRs:
//   av[j] = x[t0+rl][st*128 + w*16 + hg*8 + j]  (2 dwordx4/lane/stage, 32B)
// Wave's 64 lanes fully consume 32 rows x 64B granules (sector-coalesced).
// Removes all glds, all ds_read, all 16 barriers + fences. 2-stage register
// rings for A (2x2 float4) and B (2x6 bf16x8); waves free-run, continuous
// issue, in-flight ~16KB/wave >> requirement. Per-lane av[]/b[] values,
// MFMA order, epilogue, finalize: bit-identical to r12 (50.8us best).
// LDS (64KB) now used ONLY by the verified epilogue reduction.
__global__ __launch_bounds__(512, 4) void fused_kernel(
    const float* __restrict__ x, const bf16x8* __restrict__ Wf,
    const float* __restrict__ temp, float* __restrict__ out,
    float* __restrict__ imp_part, float* __restrict__ load_part,
    float* __restrict__ ent_part) {
  __shared__ float lds[16384];   // epilogue-only: [8 waves][32 rows][64]
  const int tid  = threadIdx.x;
  const int w    = tid >> 6;
  const int lane = tid & 63;
  const int t0   = blockIdx.x * 32;
  const int rl   = lane & 31;
  const int hg   = lane >> 5;

  float tv = temp[0];
  tv = fminf(fmaxf(tv, 0.1f), 5.0f);
  const float invT = 1.0f / tv;

  // per-lane direct A source: token rl, k-slice base w*16 + hg*8
  const float* ax = x + (size_t)(t0 + rl) * D_MODEL + w * 16 + hg * 8;

  auto loadB = [&](int st, bf16x8* bb) {
    const bf16x8* wp = Wf + (size_t)(st * 8 + w) * 128 + lane;
#pragma unroll
    for (int p = 0; p < 3; ++p)
#pragma unroll
      for (int n = 0; n < 2; ++n)
        bb[p * 2 + n] = wp[p * WF_PS + n * 64];
  };

  f32x16 acc0, acc1;
#pragma unroll
  for (int i = 0; i < 16; ++i) { acc0[i] = 0.0f; acc1[i] = 0.0f; }

  float4 a[2][2];
  bf16x8 b[2][6];

  // prologue: 2 stages of A and B in flight
  a[0][0] = *(const float4*)(ax + 0);
  a[0][1] = *(const float4*)(ax + 4);
  a[1][0] = *(const float4*)(ax + 128);
  a[1][1] = *(const float4*)(ax + 132);
  loadB(0, b[0]);
  loadB(1, b[1]);

#pragma unroll
  for (int st = 0; st < NSTG; ++st) {
    // rename current slot values (SSA; no physical copies), then reissue
    // the slot for st+2 -- loads are program-order before the uses below,
    // giving every load a full 2-stage lead; implicit per-use s_waitcnt.
    float4 a0 = a[st & 1][0];
    float4 a1 = a[st & 1][1];
    bf16x8 bb0 = b[st & 1][0], bb1 = b[st & 1][1], bb2 = b[st & 1][2];
    bf16x8 bb3 = b[st & 1][3], bb4 = b[st & 1][4], bb5 = b[st & 1][5];
    if (st + 2 < NSTG) {
      a[st & 1][0] = *(const float4*)(ax + (st + 2) * 128);
      a[st & 1][1] = *(const float4*)(ax + (st + 2) * 128 + 4);
      loadB(st + 2, b[st & 1]);
    }

    float av[8] = {a0.x, a0.y, a0.z, a0.w, a1.x, a1.y, a1.z, a1.w};
    bf16x8 ah, am, al;
#pragma unroll
    for (int j = 0; j < 8; ++j) {
      u32 hh, mm, ll;
      split3(av[j], hh, mm, ll);
      ah[j] = (short)hh; am[j] = (short)mm; al[j] = (short)ll;
    }
    acc0 = __builtin_amdgcn_mfma_f32_32x32x16_bf16(ah, bb0, acc0, 0, 0, 0);
    acc1 = __builtin_amdgcn_mfma_f32_32x32x16_bf16(ah, bb1, acc1, 0, 0, 0);
    acc0 = __builtin_amdgcn_mfma_f32_32x32x16_bf16(ah, bb2, acc0, 0, 0, 0);
    acc1 = __builtin_amdgcn_mfma_f32_32x32x16_bf16(ah, bb3, acc1, 0, 0, 0);
    acc0 = __builtin_amdgcn_mfma_f32_32x32x16_bf16(am, bb0, acc0, 0, 0, 0);
    acc1 = __builtin_amdgcn_mfma_f32_32x32x16_bf16(am, bb1, acc1, 0, 0, 0);
    acc0 = __builtin_amdgcn_mfma_f32_32x32x16_bf16(am, bb2, acc0, 0, 0, 0);
    acc1 = __builtin_amdgcn_mfma_f32_32x32x16_bf16(am, bb3, acc1, 0, 0, 0);
    acc0 = __builtin_amdgcn_mfma_f32_32x32x16_bf16(ah, bb4, acc0, 0, 0, 0);
    acc1 = __builtin_amdgcn_mfma_f32_32x32x16_bf16(ah, bb5, acc1, 0, 0, 0);
    acc0 = __builtin_amdgcn_mfma_f32_32x32x16_bf16(al, bb0, acc0, 0, 0, 0);
    acc1 = __builtin_amdgcn_mfma_f32_32x32x16_bf16(al, bb1, acc1, 0, 0, 0);
  }

  // ---- epilogue: 8-way K reduction in LDS (verified r7/r8) ----
  // per-wave disjoint regions; __syncthreads orders the cross-wave read.
  __syncthreads();
#pragma unroll
  for (int r = 0; r < 16; ++r) {
    int row = (r & 3) + ((r >> 2) << 3) + (hg << 2);
    lds[w * 2048 + row * 64 + rl]      = acc0[r];
    lds[w * 2048 + row * 64 + 32 + rl] = acc1[r];
  }
  __syncthreads();

  const int row  = tid >> 4;         // 0..31 token row
  const int colq = tid & 15;         // 16B expert chunk
  float l0 = 0.f, l1 = 0.f, l2 = 0.f, l3 = 0.f;
  for (int wv = 0; wv < 8; ++wv) {   // ascending: deterministic
    float4 v = *(const float4*)&lds[wv * 2048 + row * 64 + colq * 4];
    l0 += v.x; l1 += v.y; l2 += v.z; l3 += v.w;
  }
  l0 *= invT; l1 *= invT; l2 *= invT; l3 *= invT;

  float m = fmaxf(fmaxf(l0, l1), fmaxf(l2, l3));
#pragma unroll
  for (int d = 1; d < 16; d <<= 1) m = fmaxf(m, __shfl_xor(m, d));

  float ls0 = l0 - m, ls1 = l1 - m, ls2 = l2 - m, ls3 = l3 - m;
  float e0 = __expf(ls0), e1 = __expf(ls1), e2 = __expf(ls2), e3 = __expf(ls3);
  float ssum = e0 + e1 + e2 + e3;
  float dot  = e0 * ls0 + e1 * ls1 + e2 * ls2 + e3 * ls3;
#pragma unroll
  for (int d = 1; d < 16; d <<= 1) {
    ssum += __shfl_xor(ssum, d);
    dot  += __shfl_xor(dot, d);
  }
  const float inv_s = 1.0f / ssum;
  const float ent = __logf(ssum) - dot * inv_s;   // -sum p log p

  const int eb = colq * 4;
  float b1 = e0, b2 = -1.0f;
  int   i1 = eb, i2 = eb + 1;
  {
    float ev[3] = {e1, e2, e3};
#pragma unroll
    for (int j = 0; j < 3; ++j) {
      int ej = eb + 1 + j;
      if (better(ev[j], ej, b1, i1)) { b2 = b1; i2 = i1; b1 = ev[j]; i1 = ej; }
      else if (better(ev[j], ej, b2, i2)) { b2 = ev[j]; i2 = ej; }
    }
  }
#pragma unroll
  for (int d = 1; d < 16; d <<= 1) {
    float ob1 = __shfl_xor(b1, d), ob2 = __shfl_xor(b2, d);
    int   oi1 = __shfl_xor(i1, d), oi2 = __shfl_xor(i2, d);
    if (better(ob1, oi1, b1, i1)) {
      if (better(b1, i1, ob2, oi2)) { b2 = b1; i2 = i1; }
      else                          { b2 = ob2; i2 = oi2; }
      b1 = ob1; i1 = oi1;
    } else if (better(ob1, oi1, b2, i2)) {
      b2 = ob1; i2 = oi1;
    }
  }

  const int t = t0 + row;
  if (colq == 0) {
    out[OFF_PROBS + (size_t)t * 2 + 0] = b1 * inv_s;
    out[OFF_PROBS + (size_t)t * 2 + 1] = b2 * inv_s;
    out[OFF_IDX   + (size_t)t * 2 + 0] = (float)i1;
    out[OFF_IDX   + (size_t)t * 2 + 1] = (float)i2;
  }
  {
    float4 mv;
    mv.x = ((eb + 0 == i1) || (eb + 0 == i2)) ? 1.0f : 0.0f;
    mv.y = ((eb + 1 == i1) || (eb + 1 == i2)) ? 1.0f : 0.0f;
    mv.z = ((eb + 2 == i1) || (eb + 2 == i2)) ? 1.0f : 0.0f;
    mv.w = ((eb + 3 == i1) || (eb + 3 == i2)) ? 1.0f : 0.0f;
    *(float4*)&out[OFF_MASK + (size_t)t * N_EXP + eb] = mv;
  }

  // ---- block aux partials (deterministic fixed order) ----
  __syncthreads();
  {
    float4 p4;
    p4.x = e0 * inv_s; p4.y = e1 * inv_s; p4.z = e2 * inv_s; p4.w = e3 * inv_s;
    *(float4*)&lds[row * 64 + eb] = p4;
  }
  if (colq == 0) {
    lds[2048 + row] = (float)i1;
    lds[2080 + row] = (float)i2;
    lds[2112 + row] = ent;
  }
  __syncthreads();
  if (tid < 64) {
    float simp = 0.0f, sld = 0.0f;
    const float fe = (float)tid;
    for (int r = 0; r < 32; ++r) simp += lds[r * 64 + tid];
    for (int r = 0; r < 32; ++r)
      sld += ((lds[2048 + r] == fe) ? 1.0f : 0.0f)
           + ((lds[2080 + r] == fe) ? 1.0f : 0.0f);
    imp_part[blockIdx.x * N_EXP + tid]  = simp;
    load_part[blockIdx.x * N_EXP + tid] = sld;
    float v = (tid < 32) ? lds[2112 + tid] : 0.0f;
#pragma unroll
    for (int d = 1; d < 64; d <<= 1) v += __shfl_xor(v, d);
    if (tid == 0) ent_part[blockIdx.x] = v;
  }
}

// Finalize split (validated r11/r12, absmax unchanged): parallel partial
// reduce (64 blocks) + single-block final. Fixed order -> deterministic.
__global__ __launch_bounds__(256) void finalize_part(
    const float* __restrict__ imp_part, const float* __restrict__ load_part,
    const float* __restrict__ ent_part, float* __restrict__ imp2,
    float* __restrict__ load2, float* __restrict__ ent2) {
  __shared__ float si[4][64], sl[4][64], se[4];
  const int tid  = threadIdx.x;
  const int lane = tid & 63;
  const int q    = tid >> 6;
  const int base = blockIdx.x * 8 + q * 2;     // 2 source blocks per quarter
  float a = imp_part[(size_t)base * N_EXP + lane]
          + imp_part[(size_t)(base + 1) * N_EXP + lane];
  float b = load_part[(size_t)base * N_EXP + lane]
          + load_part[(size_t)(base + 1) * N_EXP + lane];
  si[q][lane] = a;
  sl[q][lane] = b;
  if (lane == 0) se[q] = ent_part[base] + ent_part[base + 1];
  __syncthreads();
  if (tid < 64) {
    imp2[blockIdx.x * N_EXP + tid]  = si[0][tid] + si[1][tid] + si[2][tid] + si[3][tid];
    load2[blockIdx.x * N_EXP + tid] = sl[0][tid] + sl[1][tid] + sl[2][tid] + sl[3][tid];
    if (tid == 0) ent2[blockIdx.x] = se[0] + se[1] + se[2] + se[3];
  }
}

__global__ __launch_bounds__(256) void finalize_final(
    const float* __restrict__ imp2, const float* __restrict__ load2,
    const float* __restrict__ ent2, float* __restrict__ out) {
  __shared__ float si[4][64], sl[4][64];
  const int tid  = threadIdx.x;
  const int lane = tid & 63;
  const int q    = tid >> 6;
  float a = 0.0f, b = 0.0f;
  for (int r = q * 16; r < q * 16 + 16; ++r) {   // ascending: deterministic
    a += imp2[r * N_EXP + lane];
    b += load2[r * N_EXP + lane];
  }
  si[q][lane] = a;
  sl[q][lane] = b;
  __syncthreads();
  if (tid < 64) {
    float imp = si[0][tid] + si[1][tid] + si[2][tid] + si[3][tid];
    float ld  = sl[0][tid] + sl[1][tid] + sl[2][tid] + sl[3][tid];
    imp *= (1.0f / 16384.0f);
    ld  *= (1.0f / (16384.0f + 1e-6f));
    float prod = imp * ld;
    float e = ent2[tid];
#pragma unroll
    for (int d = 1; d < 64; d <<= 1) {
      prod += __shfl_xor(prod, d);
      e    += __shfl_xor(e, d);
    }
    if (tid == 0) {
      out[OFF_AUX] = prod * 64.0f * 0.01f;
      out[OFF_ENT] = (e / 16384.0f) * 0.01f;
    }
  }
}

extern "C" void kernel_launch(void* const* d_in, const int* in_sizes, int n_in,
                              void* d_out, int out_size, void* d_ws, size_t ws_size,
                              hipStream_t stream) {
  const float* x    = (const float*)d_in[0];
  const float* W    = (const float*)d_in[1];
  const float* temp = (const float*)d_in[2];
  float* out = (float*)d_out;
  float* ws  = (float*)d_ws;

  // ws floats: Wf 196608 | imp 32768 | load 32768 | ent 512 | imp2 4096 |
  //            load2 4096 | ent2 64
  bf16x8* Wf    = (bf16x8*)ws;
  float*  imp   = ws + 196608;
  float*  ldp   = imp + NBLK * N_EXP;
  float*  entp  = ldp + NBLK * N_EXP;
  float*  imp2  = entp + NBLK;
  float*  load2 = imp2 + 64 * N_EXP;
  float*  ent2  = load2 + 64 * N_EXP;

  wprep_kernel<<<64, 256, 0, stream>>>(W, Wf);
  fused_kernel<<<NBLK, 512, 0, stream>>>(x, Wf, temp, out, imp, ldp, entp);
  finalize_part<<<64, 256, 0, stream>>>(imp, ldp, entp, imp2, load2, ent2);
  finalize_final<<<1, 256, 0, stream>>>(imp2, load2, ent2, out);
}

// Round 8
// 44.398 us; speedup vs baseline: 2.8643x; 1.2378x over previous
//
#include <hip/hip_runtime.h>
#include <hip/hip_bf16.h>
#include <math.h>

#define D_MODEL 2048
#define N_EXP   64
#define NTOK    16384           // 4 * 4096
#define NBLK    512             // NTOK / 32 tokens per block
#define NSTG    16              // K stages: 2048 / 128

typedef short bf16x8 __attribute__((ext_vector_type(8)));
typedef float f32x16 __attribute__((ext_vector_type(16)));
typedef unsigned int u32;

// out layout (floats)
#define OFF_PROBS 0
#define OFF_IDX   32768
#define OFF_MASK  65536
#define OFF_AUX   1114112
#define OFF_ENT   1114113

#define WF_PS 16384            // bf16x8 units per split-part (128 g * 2 n * 64)

#define MEMFENCE asm volatile("" ::: "memory")
// fence + barrier + fence: s_barrier alone is NOT a compiler memory fence;
// without the trailing fence the compiler may hoist next-stage LDS reads
// above the barrier (r9 failure: cross-wave stage rows read stale).
#define FULLBAR() do { MEMFENCE; __builtin_amdgcn_s_barrier(); MEMFENCE; \
                       __builtin_amdgcn_sched_barrier(0); } while (0)

__device__ __forceinline__ void split3(float xv, u32& h, u32& m, u32& l) {
  u32 xb = __builtin_bit_cast(u32, xv);
  u32 hb = xb & 0xFFFF0000u;
  float tf = xv - __builtin_bit_cast(float, hb);      // exact (Sterbenz)
  u32 tb = __builtin_bit_cast(u32, tf);
  u32 mb = tb & 0xFFFF0000u;
  float t2 = tf - __builtin_bit_cast(float, mb);      // exact; bf16-representable
  u32 lb = __builtin_bit_cast(u32, t2);
  h = hb >> 16; m = mb >> 16; l = lb >> 16;
}

__device__ __forceinline__ bool better(float a, int ia, float b, int ib) {
  return (a > b) || (a == b && ia < ib);
}

// W[64][2048] -> 3 bf16 parts in 32x32x16 B-fragment order. (verified r5-r8)
__global__ __launch_bounds__(256) void wprep_kernel(
    const float* __restrict__ W, bf16x8* __restrict__ Wf) {
  int gid  = blockIdx.x * 256 + threadIdx.x;   // 16384
  int g    = gid >> 7;
  int n    = (gid >> 6) & 1;
  int lane = gid & 63;
  int e    = n * 32 + (lane & 31);
  int k    = g * 16 + ((lane >> 5) << 3);
  const float* wr = W + (size_t)e * D_MODEL + k;
  bf16x8 hv, mv, lv;
#pragma unroll
  for (int j = 0; j < 8; ++j) {
    u32 h, m, l;
    split3(wr[j], h, m, l);
    hv[j] = (short)h; mv[j] = (short)m; lv[j] = (short)l;
  }
  Wf[gid]             = hv;
  Wf[WF_PS + gid]     = mv;
  Wf[2 * WF_PS + gid] = lv;
}

// r17: r12 structure (50.8us verified best) + PER-BLOCK K-PHASE STAGGER.
// r16 post-mortem: barrier-free register-direct ALSO ran ~3.4TB/s -> issue
// discipline, barriers, and in-flight depth are all exonerated (r12/r11/r16
// all deliver ~3.3-3.5TB/s with unrelated schedules). The limiter is the
// ADDRESS STREAM: x row stride 8192B is an exact multiple of the HBM
// channel-interleave period, so channel = f(column offset only) -- row
// number contributes nothing. All 512 blocks read the same narrow k-column
// window (~512B) at roughly the same time (identical per-stage work keeps
// them clustered), so only the few channels covering that window are busy;
// the rest idle. The 7.1TB/s fill sweeps sequentially = all channels busy.
// Fix: block b starts its K loop at logical stage st0 = b & 15 and wraps:
// kst = (st0 + st) & 15. Chip-wide column coverage now spans all 16 windows
// at every instant -> uniform channel load. Zero extra instructions; A and
// B use the same kst so each stage's MFMA contribution is unchanged -- only
// the fp32 accumulation ORDER over stages permutes (~1e-7 relative, far
// below the 2.4e-4 bf16-split error; top-k robust).
// All else bit-identical to r12: staging, swizzle, vmcnt(8/6), FULLBARs,
// epilogue, finalize split.
__global__ __launch_bounds__(512, 4) void fused_kernel(
    const float* __restrict__ x, const bf16x8* __restrict__ Wf,
    const float* __restrict__ temp, float* __restrict__ out,
    float* __restrict__ imp_part, float* __restrict__ load_part,
    float* __restrict__ ent_part) {
  __shared__ float lds[16384];   // 64 KB: 4 bufs x 32 rows x 128 floats
  const int tid  = threadIdx.x;
  const int w    = tid >> 6;
  const int lane = tid & 63;
  const int t0   = blockIdx.x * 32;
  const int rl   = lane & 31;
  const int hg   = lane >> 5;
  const int st0  = blockIdx.x & 15;      // K-phase stagger

  float tv = temp[0];
  tv = fminf(fmaxf(tv, 0.1f), 5.0f);
  const float invT = 1.0f / tv;

  // glds source bases (i=0,1): rows r0=w*4+i*2; lane covers row r0+hg,
  // physical chunk (lane&31) holds logical chunk (lane&31)^row.
  const float* gsrc[2];
#pragma unroll
  for (int i = 0; i < 2; ++i) {
    int r0  = w * 4 + i * 2;
    int row = r0 + hg;
    int sc  = rl ^ (row & 31);
    gsrc[i] = x + (size_t)(t0 + row) * D_MODEL + sc * 4;
  }

  auto stage = [&](int st) {             // st = physical stage index
    const int buf = st & 3;
    const int kst = (st0 + st) & 15;     // logical k-stage
#pragma unroll
    for (int i = 0; i < 2; ++i) {
      int r0 = w * 4 + i * 2;             // wave-uniform dest base
      __builtin_amdgcn_global_load_lds(
          (const __attribute__((address_space(1))) void*)(gsrc[i] + kst * 128),
          (__attribute__((address_space(3))) void*)(lds + buf * 4096 + r0 * 128),
          16, 0, 0);
    }
  };
  auto loadB = [&](int st, bf16x8* bb) { // st = physical stage index
    const int kst = (st0 + st) & 15;
    const bf16x8* wp = Wf + (size_t)(kst * 8 + w) * 128 + lane;
#pragma unroll
    for (int p = 0; p < 3; ++p)
#pragma unroll
      for (int n = 0; n < 2; ++n)
        bb[p * 2 + n] = wp[p * WF_PS + n * 64];
  };

  f32x16 acc0, acc1;
#pragma unroll
  for (int i = 0; i < 16; ++i) { acc0[i] = 0.0f; acc1[i] = 0.0f; }

  bf16x8 b[2][6];
  stage(0); stage(1);            // 4 glds in flight
  loadB(0, b[0]);                // 6 B-loads
  // S0 retired when newer-than-S0 (S1:2 + B0:6 = 8) are the only outstanding
  asm volatile("s_waitcnt vmcnt(8)" ::: "memory");
  FULLBAR();

  const int c0 = w * 4 + hg * 2;         // logical 16B-chunk of this lane

#pragma unroll
  for (int st = 0; st < NSTG; ++st) {
    if (st + 1 < NSTG) loadB(st + 1, b[(st + 1) & 1]);
    if (st + 2 < NSTG) stage(st + 2);

    const float* rb = lds + (st & 3) * 4096 + rl * 128;
    float4 a0 = *(const float4*)(rb + ((c0 ^ rl) << 2));
    float4 a1 = *(const float4*)(rb + (((c0 + 1) ^ rl) << 2));
    float av[8] = {a0.x, a0.y, a0.z, a0.w, a1.x, a1.y, a1.z, a1.w};
    bf16x8 ah, am, al;
#pragma unroll
    for (int j = 0; j < 8; ++j) {
      u32 hh, mm, ll;
      split3(av[j], hh, mm, ll);
      ah[j] = (short)hh; am[j] = (short)mm; al[j] = (short)ll;
    }
    const bf16x8* bb = b[st & 1];
    acc0 = __builtin_amdgcn_mfma_f32_32x32x16_bf16(ah, bb[0], acc0, 0, 0, 0);
    acc1 = __builtin_amdgcn_mfma_f32_32x32x16_bf16(ah, bb[1], acc1, 0, 0, 0);
    acc0 = __builtin_amdgcn_mfma_f32_32x32x16_bf16(ah, bb[2], acc0, 0, 0, 0);
    acc1 = __builtin_amdgcn_mfma_f32_32x32x16_bf16(ah, bb[3], acc1, 0, 0, 0);
    acc0 = __builtin_amdgcn_mfma_f32_32x32x16_bf16(am, bb[0], acc0, 0, 0, 0);
    acc1 = __builtin_amdgcn_mfma_f32_32x32x16_bf16(am, bb[1], acc1, 0, 0, 0);
    acc0 = __builtin_amdgcn_mfma_f32_32x32x16_bf16(am, bb[2], acc0, 0, 0, 0);
    acc1 = __builtin_amdgcn_mfma_f32_32x32x16_bf16(am, bb[3], acc1, 0, 0, 0);
    acc0 = __builtin_amdgcn_mfma_f32_32x32x16_bf16(ah, bb[4], acc0, 0, 0, 0);
    acc1 = __builtin_amdgcn_mfma_f32_32x32x16_bf16(ah, bb[5], acc1, 0, 0, 0);
    acc0 = __builtin_amdgcn_mfma_f32_32x32x16_bf16(al, bb[0], acc0, 0, 0, 0);
    acc1 = __builtin_amdgcn_mfma_f32_32x32x16_bf16(al, bb[1], acc1, 0, 0, 0);

    // end-of-stage: S(st+1) retired iff newest 8 (B(st+1):6 + S(st+2):2)
    // are the only outstanding. Tail st=14: only B15:6 newer -> vmcnt(6).
    if (st < NSTG - 2) {
      asm volatile("s_waitcnt vmcnt(8)" ::: "memory");
      FULLBAR();
    } else if (st == NSTG - 2) {
      asm volatile("s_waitcnt vmcnt(6)" ::: "memory");
      FULLBAR();
    }
  }

  // ---- epilogue: 8-way K reduction in LDS (verified r7/r8) ----
  __syncthreads();
#pragma unroll
  for (int r = 0; r < 16; ++r) {
    int row = (r & 3) + ((r >> 2) << 3) + (hg << 2);
    lds[w * 2048 + row * 64 + rl]      = acc0[r];
    lds[w * 2048 + row * 64 + 32 + rl] = acc1[r];
  }
  __syncthreads();

  const int row  = tid >> 4;         // 0..31 token row
  const int colq = tid & 15;         // 16B expert chunk
  float l0 = 0.f, l1 = 0.f, l2 = 0.f, l3 = 0.f;
  for (int wv = 0; wv < 8; ++wv) {   // ascending: deterministic
    float4 v = *(const float4*)&lds[wv * 2048 + row * 64 + colq * 4];
    l0 += v.x; l1 += v.y; l2 += v.z; l3 += v.w;
  }
  l0 *= invT; l1 *= invT; l2 *= invT; l3 *= invT;

  float m = fmaxf(fmaxf(l0, l1), fmaxf(l2, l3));
#pragma unroll
  for (int d = 1; d < 16; d <<= 1) m = fmaxf(m, __shfl_xor(m, d));

  float ls0 = l0 - m, ls1 = l1 - m, ls2 = l2 - m, ls3 = l3 - m;
  float e0 = __expf(ls0), e1 = __expf(ls1), e2 = __expf(ls2), e3 = __expf(ls3);
  float ssum = e0 + e1 + e2 + e3;
  float dot  = e0 * ls0 + e1 * ls1 + e2 * ls2 + e3 * ls3;
#pragma unroll
  for (int d = 1; d < 16; d <<= 1) {
    ssum += __shfl_xor(ssum, d);
    dot  += __shfl_xor(dot, d);
  }
  const float inv_s = 1.0f / ssum;
  const float ent = __logf(ssum) - dot * inv_s;   // -sum p log p

  const int eb = colq * 4;
  float b1 = e0, b2 = -1.0f;
  int   i1 = eb, i2 = eb + 1;
  {
    float ev[3] = {e1, e2, e3};
#pragma unroll
    for (int j = 0; j < 3; ++j) {
      int ej = eb + 1 + j;
      if (better(ev[j], ej, b1, i1)) { b2 = b1; i2 = i1; b1 = ev[j]; i1 = ej; }
      else if (better(ev[j], ej, b2, i2)) { b2 = ev[j]; i2 = ej; }
    }
  }
#pragma unroll
  for (int d = 1; d < 16; d <<= 1) {
    float ob1 = __shfl_xor(b1, d), ob2 = __shfl_xor(b2, d);
    int   oi1 = __shfl_xor(i1, d), oi2 = __shfl_xor(i2, d);
    if (better(ob1, oi1, b1, i1)) {
      if (better(b1, i1, ob2, oi2)) { b2 = b1; i2 = i1; }
      else                          { b2 = ob2; i2 = oi2; }
      b1 = ob1; i1 = oi1;
    } else if (better(ob1, oi1, b2, i2)) {
      b2 = ob1; i2 = oi1;
    }
  }

  const int t = t0 + row;
  if (colq == 0) {
    out[OFF_PROBS + (size_t)t * 2 + 0] = b1 * inv_s;
    out[OFF_PROBS + (size_t)t * 2 + 1] = b2 * inv_s;
    out[OFF_IDX   + (size_t)t * 2 + 0] = (float)i1;
    out[OFF_IDX   + (size_t)t * 2 + 1] = (float)i2;
  }
  {
    float4 mv;
    mv.x = ((eb + 0 == i1) || (eb + 0 == i2)) ? 1.0f : 0.0f;
    mv.y = ((eb + 1 == i1) || (eb + 1 == i2)) ? 1.0f : 0.0f;
    mv.z = ((eb + 2 == i1) || (eb + 2 == i2)) ? 1.0f : 0.0f;
    mv.w = ((eb + 3 == i1) || (eb + 3 == i2)) ? 1.0f : 0.0f;
    *(float4*)&out[OFF_MASK + (size_t)t * N_EXP + eb] = mv;
  }

  // ---- block aux partials (deterministic fixed order) ----
  __syncthreads();
  {
    float4 p4;
    p4.x = e0 * inv_s; p4.y = e1 * inv_s; p4.z = e2 * inv_s; p4.w = e3 * inv_s;
    *(float4*)&lds[row * 64 + eb] = p4;
  }
  if (colq == 0) {
    lds[2048 + row] = (float)i1;
    lds[2080 + row] = (float)i2;
    lds[2112 + row] = ent;
  }
  __syncthreads();
  if (tid < 64) {
    float simp = 0.0f, sld = 0.0f;
    const float fe = (float)tid;
    for (int r = 0; r < 32; ++r) simp += lds[r * 64 + tid];
    for (int r = 0; r < 32; ++r)
      sld += ((lds[2048 + r] == fe) ? 1.0f : 0.0f)
           + ((lds[2080 + r] == fe) ? 1.0f : 0.0f);
    imp_part[blockIdx.x * N_EXP + tid]  = simp;
    load_part[blockIdx.x * N_EXP + tid] = sld;
    float v = (tid < 32) ? lds[2112 + tid] : 0.0f;
#pragma unroll
    for (int d = 1; d < 64; d <<= 1) v += __shfl_xor(v, d);
    if (tid == 0) ent_part[blockIdx.x] = v;
  }
}

// Finalize split (validated r11/r12, absmax unchanged): parallel partial
// reduce (64 blocks) + single-block final. Fixed order -> deterministic.
__global__ __launch_bounds__(256) void finalize_part(
    const float* __restrict__ imp_part, const float* __restrict__ load_part,
    const float* __restrict__ ent_part, float* __restrict__ imp2,
    float* __restrict__ load2, float* __restrict__ ent2) {
  __shared__ float si[4][64], sl[4][64], se[4];
  const int tid  = threadIdx.x;
  const int lane = tid & 63;
  const int q    = tid >> 6;
  const int base = blockIdx.x * 8 + q * 2;     // 2 source blocks per quarter
  float a = imp_part[(size_t)base * N_EXP + lane]
          + imp_part[(size_t)(base + 1) * N_EXP + lane];
  float b = load_part[(size_t)base * N_EXP + lane]
          + load_part[(size_t)(base + 1) * N_EXP + lane];
  si[q][lane] = a;
  sl[q][lane] = b;
  if (lane == 0) se[q] = ent_part[base] + ent_part[base + 1];
  __syncthreads();
  if (tid < 64) {
    imp2[blockIdx.x * N_EXP + tid]  = si[0][tid] + si[1][tid] + si[2][tid] + si[3][tid];
    load2[blockIdx.x * N_EXP + tid] = sl[0][tid] + sl[1][tid] + sl[2][tid] + sl[3][tid];
    if (tid == 0) ent2[blockIdx.x] = se[0] + se[1] + se[2] + se[3];
  }
}

__global__ __launch_bounds__(256) void finalize_final(
    const float* __restrict__ imp2, const float* __restrict__ load2,
    const float* __restrict__ ent2, float* __restrict__ out) {
  __shared__ float si[4][64], sl[4][64];
  const int tid  = threadIdx.x;
  const int lane = tid & 63;
  const int q    = tid >> 6;
  float a = 0.0f, b = 0.0f;
  for (int r = q * 16; r < q * 16 + 16; ++r) {   // ascending: deterministic
    a += imp2[r * N_EXP + lane];
    b += load2[r * N_EXP + lane];
  }
  si[q][lane] = a;
  sl[q][lane] = b;
  __syncthreads();
  if (tid < 64) {
    float imp = si[0][tid] + si[1][tid] + si[2][tid] + si[3][tid];
    float ld  = sl[0][tid] + sl[1][tid] + sl[2][tid] + sl[3][tid];
    imp *= (1.0f / 16384.0f);
    ld  *= (1.0f / (16384.0f + 1e-6f));
    float prod = imp * ld;
    float e = ent2[tid];
#pragma unroll
    for (int d = 1; d < 64; d <<= 1) {
      prod += __shfl_xor(prod, d);
      e    += __shfl_xor(e, d);
    }
    if (tid == 0) {
      out[OFF_AUX] = prod * 64.0f * 0.01f;
      out[OFF_ENT] = (e / 16384.0f) * 0.01f;
    }
  }
}

extern "C" void kernel_launch(void* const* d_in, const int* in_sizes, int n_in,
                              void* d_out, int out_size, void* d_ws, size_t ws_size,
                              hipStream_t stream) {
  const float* x    = (const float*)d_in[0];
  const float* W    = (const float*)d_in[1];
  const float* temp = (const float*)d_in[2];
  float* out = (float*)d_out;
  float* ws  = (float*)d_ws;

  // ws floats: Wf 196608 | imp 32768 | load 32768 | ent 512 | imp2 4096 |
  //            load2 4096 | ent2 64
  bf16x8* Wf    = (bf16x8*)ws;
  float*  imp   = ws + 196608;
  float*  ldp   = imp + NBLK * N_EXP;
  float*  entp  = ldp + NBLK * N_EXP;
  float*  imp2  = entp + NBLK;
  float*  load2 = imp2 + 64 * N_EXP;
  float*  ent2  = load2 + 64 * N_EXP;

  wprep_kernel<<<64, 256, 0, stream>>>(W, Wf);
  fused_kernel<<<NBLK, 512, 0, stream>>>(x, Wf, temp, out, imp, ldp, entp);
  finalize_part<<<64, 256, 0, stream>>>(imp, ldp, entp, imp2, load2, ent2);
  finalize_final<<<1, 256, 0, stream>>>(imp2, load2, ent2, out);
}